// Round 13
// baseline (84.396 us; speedup 1.0000x reference)
//
#include <hip/hip_runtime.h>
#include <hip/hip_bf16.h>
#include <math.h>

#define BN 8192
#define DK 128
#define NSLOT 32           // 32 row-groups of 256 rows
#define NTILES (NSLOT * (NSLOT + 1) / 2)   // 528 triangular tiles
#define MARGIN_F 1.0f

// ---------------- workspace layout (float-slot offsets from d_ws) -------------
// Eb  : bf16 8192x128 (B-side)            = 2MB
// EbS : bf16 8192x128 scaled by -128 (A)  = 2MB
// sq64: f32 [BN] 64*sum(x^2)
// posV/negV: f32 [NSLOT][BN] mined 64*d2 values
// red : ull sum + uint counter (16B)
#define OFF_EBS  524288
#define OFF_SQ   1048576
#define OFF_POSV (OFF_SQ + BN)
#define OFF_NEGV (OFF_POSV + NSLOT * BN)
#define OFF_RED  (OFF_NEGV + NSLOT * BN)

typedef __attribute__((ext_vector_type(8))) short bf16x8;
typedef __attribute__((ext_vector_type(4))) float f32x4;

__device__ __forceinline__ unsigned short f2bf(float f) {
    __hip_bfloat16 h = __float2bfloat16(f);
    return *reinterpret_cast<unsigned short*>(&h);
}

__device__ __forceinline__ void gload_lds16(const void* g, void* s) {
    __builtin_amdgcn_global_load_lds(
        (const __attribute__((address_space(1))) void*)g,
        (__attribute__((address_space(3))) void*)s, 16, 0, 0);
}

// ---------------- prep: bf16 tables (plain + -128-scaled) + 64*rowsq ----------
__global__ __launch_bounds__(256) void k_prep(const float* __restrict__ emb,
                                              unsigned short* __restrict__ Eb,
                                              unsigned short* __restrict__ EbS,
                                              float* __restrict__ sq64) {
    int row  = blockIdx.x * 4 + (threadIdx.x >> 6);
    int lane = threadIdx.x & 63;
    float2 v = ((const float2*)(emb + (size_t)row * DK))[lane];
    ushort2 o;  o.x  = f2bf(v.x);           o.y  = f2bf(v.y);
    ushort2 os; os.x = f2bf(v.x * -128.0f); os.y = f2bf(v.y * -128.0f);
    ((ushort2*)(Eb  + (size_t)row * DK))[lane] = o;
    ((ushort2*)(EbS + (size_t)row * DK))[lane] = os;
    float s = v.x * v.x + v.y * v.y;
    #pragma unroll
    for (int m = 32; m; m >>= 1) s += __shfl_xor(s, m);
    if (lane == 0) sq64[row] = 64.0f * s;
}

// ---------------- symmetric fused MFMA Gram + batch-hard VALUE mining ---------
// 528 blocks = upper-triangular 256x256 tiles (I<=J). Block = 4 waves x 64
// i-rows; cols = J-group 256, in 2 x 128-col dbuf LDS intervals (async
// global_load_lds, source-preswizzled). Mine v = acc + 64*sq_i = 64*d2
// (symmetric). Row-side winners -> slot J (rows of I); col-side winners
// (off-diag only: in-lane reduce over mi,v + shfl over lh + LDS colbuf +
// block combine) -> slot I (rows of J). Each (slot,row) written exactly once.
// Self-pairs on diagonal: v_self <= ~64 << true positive v (~16k) -> safe.
__global__ __launch_bounds__(256)
void k_mine9(const unsigned short* __restrict__ Eb,
             const unsigned short* __restrict__ EbS,
             const float* __restrict__ sq64,
             const int* __restrict__ tgt,
             float* __restrict__ posV, float* __restrict__ negV) {
    __shared__ __align__(16) char Blds[2][2][16384];   // [buf][half][16KB]
    __shared__ float colP[4][256], colN[4][256];       // per-wave col winners

    const int tid = threadIdx.x;
    const int w   = tid >> 6;
    const int l   = tid & 63;
    const int lh  = l >> 4;
    const int tx  = l & 15;

    // triangular unrank: block -> (I, J), J >= I
    int I = 0, rem = blockIdx.x;
    while (rem >= NSLOT - I) { rem -= NSLOT - I; ++I; }
    const int J = I + rem;
    const bool diag = (I == J);
    const int i0w = I * 256 + w * 64;
    const int jb  = J * 256;
    const char* EbB = (const char*)Eb;

    // A fragments (64 rows per wave) from the -128-scaled table
    bf16x8 A[4][4];
    #pragma unroll
    for (int mi = 0; mi < 4; ++mi) {
        const char* rp = (const char*)EbS + (size_t)(i0w + mi * 16 + tx) * 256 + lh * 16;
        #pragma unroll
        for (int ks = 0; ks < 4; ++ks)
            A[mi][ks] = *(const bf16x8*)(rp + ks * 64);
    }

    // per-lane i-row metadata: si = 64*sq_i, t8 = target
    float si[16]; int t8[16];
    #pragma unroll
    for (int mi = 0; mi < 4; ++mi) {
        float4 s4 = *(const float4*)(sq64 + i0w + mi * 16 + lh * 4);
        si[mi * 4 + 0] = s4.x; si[mi * 4 + 1] = s4.y;
        si[mi * 4 + 2] = s4.z; si[mi * 4 + 3] = s4.w;
        int4 q = *(const int4*)(tgt + i0w + mi * 16 + lh * 4);
        t8[mi * 4 + 0] = q.x; t8[mi * 4 + 1] = q.y;
        t8[mi * 4 + 2] = q.z; t8[mi * 4 + 3] = q.w;
    }

    float pp[16], nn[16];
    #pragma unroll
    for (int r = 0; r < 16; ++r) { pp[r] = -INFINITY; nn[r] = INFINITY; }

    // stage one 64-col subtile (16KB), source-preswizzled:
    // LDS[row][c] = Eb[j0+row][c ^ (row&7)], c = 16B chunk; dst linear.
    auto stage64 = [&](char* dst, int jcol0) {
        const char* S = EbB + (size_t)jcol0 * 256;
        #pragma unroll
        for (int q = 0; q < 4; ++q) {
            int f  = tid + 256 * q;           // 0..1023
            int gr = f >> 4;                  // subtile row 0..63
            int sc = (f & 15) ^ (gr & 7);     // swizzled source chunk
            gload_lds16(S + gr * 256 + sc * 16, dst + w * 1024 + q * 4096);
        }
    };

    stage64(Blds[0][0], jb);
    stage64(Blds[0][1], jb + 64);
    __syncthreads();

    for (int g = 0; g < 2; ++g) {
        if (g == 0) {                          // async prefetch cols 128..255
            stage64(Blds[1][0], jb + 128);
            stage64(Blds[1][1], jb + 192);
        }
        const int j0 = jb + g * 128;

        // per-interval column metadata (hoisted; hides under MFMA)
        float sqv[4][2]; int tjv[4][2];
        #pragma unroll
        for (int s = 0; s < 4; ++s)
            #pragma unroll
            for (int u = 0; u < 2; ++u) {
                int j = j0 + s * 32 + u * 16 + tx;
                sqv[s][u] = sq64[j]; tjv[s][u] = tgt[j];
            }

        #pragma unroll
        for (int s = 0; s < 4; ++s) {           // 32-col subtiles
            f32x4 acc[4][2];
            #pragma unroll
            for (int mi = 0; mi < 4; ++mi)
                #pragma unroll
                for (int u = 0; u < 2; ++u) {
                    float sv = sqv[s][u];
                    f32x4 a0 = {sv, sv, sv, sv};
                    acc[mi][u] = a0;
                }

            const char* base = Blds[g][s >> 1];
            #pragma unroll
            for (int ks = 0; ks < 4; ++ks) {
                bf16x8 Bf[2];
                #pragma unroll
                for (int u = 0; u < 2; ++u) {
                    int row = (s & 1) * 32 + u * 16 + tx;
                    int c   = (ks * 4 + lh) ^ (row & 7);
                    Bf[u] = *(const bf16x8*)(base + row * 256 + c * 16);
                }
                __builtin_amdgcn_s_setprio(1);
                #pragma unroll
                for (int mi = 0; mi < 4; ++mi)
                    #pragma unroll
                    for (int u = 0; u < 2; ++u)
                        acc[mi][u] = __builtin_amdgcn_mfma_f32_16x16x32_bf16(
                            A[mi][ks], Bf[u], acc[mi][u], 0, 0, 0);
                __builtin_amdgcn_s_setprio(0);
            }

            // epilogue: v = acc + 64*sq_i = 64*d2 (symmetric value)
            const int tj0 = tjv[s][0], tj1 = tjv[s][1];
            float pc0 = -INFINITY, pc1 = -INFINITY;
            float nc0 =  INFINITY, nc1 =  INFINITY;
            #pragma unroll
            for (int mi = 0; mi < 4; ++mi) {
                #pragma unroll
                for (int v = 0; v < 4; ++v) {
                    const int r = mi * 4 + v;
                    const int trg = t8[r];
                    float v0 = acc[mi][0][v] + si[r];
                    float v1 = acc[mi][1][v] + si[r];
                    bool s0 = (tj0 == trg);
                    bool s1 = (tj1 == trg);
                    float a0 = s0 ? v0 : -INFINITY;
                    float b0 = s0 ?  INFINITY : v0;
                    float a1 = s1 ? v1 : -INFINITY;
                    float b1 = s1 ?  INFINITY : v1;
                    pp[r] = fmaxf(fmaxf(pp[r], a0), a1);   // v_max3_f32
                    nn[r] = fminf(fminf(nn[r], b0), b1);   // v_min3_f32
                    if (!diag) {
                        pc0 = fmaxf(pc0, a0); pc1 = fmaxf(pc1, a1);
                        nc0 = fminf(nc0, b0); nc1 = fminf(nc1, b1);
                    }
                }
            }
            if (!diag) {   // col-side: reduce over lh (4 lanes per column)
                pc0 = fmaxf(pc0, __shfl_xor(pc0, 16));
                pc0 = fmaxf(pc0, __shfl_xor(pc0, 32));
                pc1 = fmaxf(pc1, __shfl_xor(pc1, 16));
                pc1 = fmaxf(pc1, __shfl_xor(pc1, 32));
                nc0 = fminf(nc0, __shfl_xor(nc0, 16));
                nc0 = fminf(nc0, __shfl_xor(nc0, 32));
                nc1 = fminf(nc1, __shfl_xor(nc1, 16));
                nc1 = fminf(nc1, __shfl_xor(nc1, 32));
                if (lh == 0) {
                    int c0 = g * 128 + s * 32 + tx;
                    colP[w][c0]      = pc0; colN[w][c0]      = nc0;
                    colP[w][c0 + 16] = pc1; colN[w][c0 + 16] = nc1;
                }
            }
        }

        __syncthreads();   // buf reads done; prefetch complete; colbuf visible
    }

    // row-side outputs -> slot J (rows of group I)
    #pragma unroll
    for (int r = 0; r < 16; ++r) {
        float p = pp[r], n = nn[r];
        #pragma unroll
        for (int m = 1; m < 16; m <<= 1) {
            p = fmaxf(p, __shfl_xor(p, m));
            n = fminf(n, __shfl_xor(n, m));
        }
        if (tx == 0) {
            int row = i0w + (r >> 2) * 16 + lh * 4 + (r & 3);
            posV[J * BN + row] = p;
            negV[J * BN + row] = n;
        }
    }

    // col-side outputs -> slot I (rows of group J); colbuf synced at loop end
    if (!diag) {
        int c = tid;
        float p = fmaxf(fmaxf(colP[0][c], colP[1][c]),
                        fmaxf(colP[2][c], colP[3][c]));
        float n = fminf(fminf(colN[0][c], colN[1][c]),
                        fminf(colN[2][c], colN[3][c]));
        posV[I * BN + jb + c] = p;
        negV[I * BN + jb + c] = n;
    }
}

// ---------------- combine slots + loss + mean (fused, deterministic) ----------
// 32 blocks x 256 threads, 1 row/thread, streaming loads. Stored value is
// 64*d2 directly. Block-sum f32 (fixed order) -> 2^-24 fixed point -> 32
// integer atomics (commutative-exact) -> last block writes mean.
__global__ __launch_bounds__(256) void k_finm(const float* __restrict__ posV,
                                              const float* __restrict__ negV,
                                              unsigned long long* __restrict__ red,
                                              float* __restrict__ out) {
    int row  = blockIdx.x * 256 + threadIdx.x;
    int lane = threadIdx.x & 63;

    float p = -INFINITY, n = INFINITY;
    #pragma unroll
    for (int s = 0; s < NSLOT; ++s) {
        p = fmaxf(p, posV[s * BN + row]);
        n = fminf(n, negV[s * BN + row]);
    }
    float d2p = fmaxf(p, 0.f) * 0.015625f;
    float d2n = fmaxf(n, 0.f) * 0.015625f;
    float lo  = sqrtf(d2p) - sqrtf(d2n) + MARGIN_F;
    lo = lo > 0.f ? lo : 0.f;

    #pragma unroll
    for (int m = 32; m; m >>= 1) lo += __shfl_xor(lo, m);
    __shared__ float part[4];
    if (lane == 0) part[threadIdx.x >> 6] = lo;
    __syncthreads();
    if (threadIdx.x == 0) {
        float bs = part[0] + part[1] + part[2] + part[3];
        atomicAdd(red, (unsigned long long)(bs * 16777216.0f));
        __threadfence();
        unsigned int t = atomicAdd((unsigned int*)(red + 1), 1u);
        if (t == gridDim.x - 1) {
            unsigned long long tot = atomicAdd(red, 0ULL);
            out[0] = (float)((double)tot / 16777216.0 / (double)BN);
        }
    }
}

extern "C" void kernel_launch(void* const* d_in, const int* in_sizes, int n_in,
                              void* d_out, int out_size, void* d_ws, size_t ws_size,
                              hipStream_t stream) {
    const float* emb = (const float*)d_in[0];
    const int*   tgt = (const int*)d_in[1];
    float* out = (float*)d_out;

    float* wsf = (float*)d_ws;
    unsigned short* Eb  = (unsigned short*)wsf;
    unsigned short* EbS = (unsigned short*)(wsf + OFF_EBS);
    float* sq64 = wsf + OFF_SQ;
    float* posV = wsf + OFF_POSV;
    float* negV = wsf + OFF_NEGV;
    unsigned long long* red = (unsigned long long*)(wsf + OFF_RED);

    hipMemsetAsync(red, 0, 16, stream);
    k_prep<<<BN / 4, 256, 0, stream>>>(emb, Eb, EbS, sq64);
    k_mine9<<<NTILES, 256, 0, stream>>>(Eb, EbS, sq64, tgt, posV, negV);
    k_finm<<<BN / 256, 256, 0, stream>>>(posV, negV, red, out);
}

// Round 14
// 40.630 us; speedup vs baseline: 2.0772x; 2.0772x over previous
//
#include <hip/hip_runtime.h>
#include <hip/hip_bf16.h>
#include <math.h>

#define BN 8192
#define DK 128
#define NSPLIT 16
#define JR (BN / NSPLIT)    // 512 cols per split
#define NG (JR / 128)       // 4 intervals of 128 cols
#define MARGIN_F 1.0f

// ---------------- workspace layout (float-slot offsets from d_ws) -------------
// Eb  : bf16 8192x128 (B-side)            = 2MB
// EbS : bf16 8192x128 scaled by -128 (A)  = 2MB
// sq64: f32 [BN]  64*sum(x^2)
// posV/negV: f32 [NSPLIT][BN] mined key values (64*(sq_j-2dot))
// red : ull sum + uint counter (16B)
#define OFF_EBS  524288
#define OFF_SQ   1048576
#define OFF_POSV (OFF_SQ + BN)
#define OFF_NEGV (OFF_POSV + NSPLIT * BN)
#define OFF_RED  (OFF_NEGV + NSPLIT * BN)

typedef __attribute__((ext_vector_type(8))) short bf16x8;
typedef __attribute__((ext_vector_type(4))) float f32x4;

__device__ __forceinline__ unsigned short f2bf(float f) {
    __hip_bfloat16 h = __float2bfloat16(f);
    return *reinterpret_cast<unsigned short*>(&h);
}

__device__ __forceinline__ void gload_lds16(const void* g, void* s) {
    __builtin_amdgcn_global_load_lds(
        (const __attribute__((address_space(1))) void*)g,
        (__attribute__((address_space(3))) void*)s, 16, 0, 0);
}

// ---------------- prep: bf16 tables + 64*rowsq + zero the reduction cell ------
__global__ __launch_bounds__(256) void k_prep(const float* __restrict__ emb,
                                              unsigned short* __restrict__ Eb,
                                              unsigned short* __restrict__ EbS,
                                              float* __restrict__ sq64,
                                              unsigned long long* __restrict__ red) {
    if (blockIdx.x == 0 && threadIdx.x == 0) {   // replaces hipMemsetAsync
        red[0] = 0ULL;
        red[1] = 0ULL;
    }
    int row  = blockIdx.x * 4 + (threadIdx.x >> 6);
    int lane = threadIdx.x & 63;
    float2 v = ((const float2*)(emb + (size_t)row * DK))[lane];
    ushort2 o;  o.x  = f2bf(v.x);           o.y  = f2bf(v.y);
    ushort2 os; os.x = f2bf(v.x * -128.0f); os.y = f2bf(v.y * -128.0f);
    ((ushort2*)(Eb  + (size_t)row * DK))[lane] = o;
    ((ushort2*)(EbS + (size_t)row * DK))[lane] = os;
    float s = v.x * v.x + v.y * v.y;
    #pragma unroll
    for (int m = 32; m; m >>= 1) s += __shfl_xor(s, m);
    if (lane == 0) sq64[row] = 64.0f * s;
}

// ---------------- fused MFMA Gram + batch-hard VALUE mining -------------------
// Proven round-12 geometry: 512 blocks = 32 igroups x 16 splits; block =
// 4 waves x 64 i-rows covering 256 rows x 512 cols; B in 128-col intervals,
// double-buffered 2x32KB LDS via async global_load_lds; 4 barriers.
// Mine the f32 KEY VALUE only (no indices). acc init = 64*sq_j; MFMA adds
// (-128 x_i)·x_j  =>  acc = 64*(sq_j - 2 dot) = 64*key. Epilogue per element:
// cmp + cndmask(-INF/+INF) + v_max3/min3_f32.
// Self-pair: key_self = -64*sq_i << any real positive key -> never wins max.
// DO NOT add min-waves launch bounds (r6/r8: spill cliff) or grow state
// (r13: VGPR 224 -> occupancy collapse). This configuration is the optimum.
__global__ __launch_bounds__(256)
void k_mine8(const unsigned short* __restrict__ Eb,
             const unsigned short* __restrict__ EbS,
             const float* __restrict__ sq64,
             const int* __restrict__ tgt,
             float* __restrict__ posV, float* __restrict__ negV) {
    __shared__ __align__(16) char Blds[2][2][16384];   // [buf][half][16KB]

    const int tid = threadIdx.x;
    const int w   = tid >> 6;
    const int l   = tid & 63;
    const int lh  = l >> 4;
    const int tx  = l & 15;
    const int igroup = blockIdx.x >> 4;   // 0..31
    const int split  = blockIdx.x & 15;   // 0..15
    const int i0w = igroup * 256 + w * 64;
    const int jb  = split * JR;
    const char* EbB = (const char*)Eb;

    // A fragments (64 rows per wave) from the -128-scaled table
    bf16x8 A[4][4];
    #pragma unroll
    for (int mi = 0; mi < 4; ++mi) {
        const char* rp = (const char*)EbS + (size_t)(i0w + mi * 16 + tx) * 256 + lh * 16;
        #pragma unroll
        for (int ks = 0; ks < 4; ++ks)
            A[mi][ks] = *(const bf16x8*)(rp + ks * 64);
    }

    // per-lane i-row targets: t8[mi*4+v] = tgt[i0w + mi*16 + lh*4 + v]
    int t8[16];
    #pragma unroll
    for (int mi = 0; mi < 4; ++mi) {
        int4 q = *(const int4*)(tgt + i0w + mi * 16 + lh * 4);
        t8[mi * 4 + 0] = q.x; t8[mi * 4 + 1] = q.y;
        t8[mi * 4 + 2] = q.z; t8[mi * 4 + 3] = q.w;
    }

    float pp[16], nn[16];
    #pragma unroll
    for (int r = 0; r < 16; ++r) { pp[r] = -INFINITY; nn[r] = INFINITY; }

    // stage one 64-col subtile (16KB), source-preswizzled:
    // LDS[row][c] = Eb[j0+row][c ^ (row&7)], c = 16B chunk; dst linear.
    auto stage64 = [&](char* dst, int jcol0) {
        const char* S = EbB + (size_t)jcol0 * 256;
        #pragma unroll
        for (int q = 0; q < 4; ++q) {
            int f  = tid + 256 * q;           // 0..1023
            int gr = f >> 4;                  // subtile row 0..63
            int sc = (f & 15) ^ (gr & 7);     // swizzled source chunk
            gload_lds16(S + gr * 256 + sc * 16, dst + w * 1024 + q * 4096);
        }
    };

    stage64(Blds[0][0], jb);
    stage64(Blds[0][1], jb + 64);
    __syncthreads();

    for (int g = 0; g < NG; ++g) {
        const int buf = g & 1;
        if (g + 1 < NG) {                       // async prefetch next 128 cols
            stage64(Blds[buf ^ 1][0], jb + (g + 1) * 128);
            stage64(Blds[buf ^ 1][1], jb + (g + 1) * 128 + 64);
        }
        const int j0 = jb + g * 128;

        // per-interval column metadata (hoisted; hides under MFMA)
        float sqv[4][2]; int tjv[4][2];
        #pragma unroll
        for (int s = 0; s < 4; ++s)
            #pragma unroll
            for (int u = 0; u < 2; ++u) {
                int j = j0 + s * 32 + u * 16 + tx;
                sqv[s][u] = sq64[j]; tjv[s][u] = tgt[j];
            }

        #pragma unroll
        for (int s = 0; s < 4; ++s) {           // 32-col subtiles
            f32x4 acc[4][2];
            #pragma unroll
            for (int mi = 0; mi < 4; ++mi)
                #pragma unroll
                for (int u = 0; u < 2; ++u) {
                    float sv = sqv[s][u];
                    f32x4 a0 = {sv, sv, sv, sv};
                    acc[mi][u] = a0;
                }

            const char* base = Blds[buf][s >> 1];
            #pragma unroll
            for (int ks = 0; ks < 4; ++ks) {
                bf16x8 Bf[2];
                #pragma unroll
                for (int u = 0; u < 2; ++u) {
                    int row = (s & 1) * 32 + u * 16 + tx;
                    int c   = (ks * 4 + lh) ^ (row & 7);
                    Bf[u] = *(const bf16x8*)(base + row * 256 + c * 16);
                }
                __builtin_amdgcn_s_setprio(1);
                #pragma unroll
                for (int mi = 0; mi < 4; ++mi)
                    #pragma unroll
                    for (int u = 0; u < 2; ++u)
                        acc[mi][u] = __builtin_amdgcn_mfma_f32_16x16x32_bf16(
                            A[mi][ks], Bf[u], acc[mi][u], 0, 0, 0);
                __builtin_amdgcn_s_setprio(0);
            }

            // value-mining epilogue: acc == 64*(sq_j - 2 dot) == 64*key
            const int tj0 = tjv[s][0], tj1 = tjv[s][1];
            #pragma unroll
            for (int mi = 0; mi < 4; ++mi) {
                #pragma unroll
                for (int v = 0; v < 4; ++v) {
                    const int r = mi * 4 + v;
                    const int trg = t8[r];
                    float k0 = acc[mi][0][v];
                    float k1 = acc[mi][1][v];
                    bool s0 = (tj0 == trg);
                    bool s1 = (tj1 == trg);
                    float a0 = s0 ? k0 : -INFINITY;
                    float b0 = s0 ? INFINITY : k0;
                    float a1 = s1 ? k1 : -INFINITY;
                    float b1 = s1 ? INFINITY : k1;
                    pp[r] = fmaxf(fmaxf(pp[r], a0), a1);   // -> v_max3_f32
                    nn[r] = fminf(fminf(nn[r], b0), b1);   // -> v_min3_f32
                }
            }
        }

        __syncthreads();   // all waves done reading buf; prefetch complete
    }

    // reduce across the 16 tx lanes
    #pragma unroll
    for (int r = 0; r < 16; ++r) {
        float p = pp[r], n = nn[r];
        #pragma unroll
        for (int m = 1; m < 16; m <<= 1) {
            p = fmaxf(p, __shfl_xor(p, m));
            n = fminf(n, __shfl_xor(n, m));
        }
        if (tx == 0) {
            int row = i0w + (r >> 2) * 16 + lh * 4 + (r & 3);
            posV[split * BN + row] = p;
            negV[split * BN + row] = n;
        }
    }
}

// ---------------- combine splits + loss + mean (fused, deterministic) ---------
// 32 blocks x 256 threads, 1 row/thread, streaming loads (no gathers).
// d2 = (key64 + 64*sq_i)/64, clamped >= 0 (matches ref's maximum(d2,0)).
// Block-sum f32 (fixed order) -> 2^-24 fixed-point -> 32 integer atomics
// (commutative-exact) -> last block writes the mean.
__global__ __launch_bounds__(256) void k_finm(const float* __restrict__ sq64,
                                              const float* __restrict__ posV,
                                              const float* __restrict__ negV,
                                              unsigned long long* __restrict__ red,
                                              float* __restrict__ out) {
    int row  = blockIdx.x * 256 + threadIdx.x;
    int lane = threadIdx.x & 63;

    float p = -INFINITY, n = INFINITY;
    #pragma unroll
    for (int s = 0; s < NSPLIT; ++s) {
        p = fmaxf(p, posV[s * BN + row]);
        n = fminf(n, negV[s * BN + row]);
    }
    float s64 = sq64[row];
    float d2p = fmaxf(p + s64, 0.f) * 0.015625f;
    float d2n = fmaxf(n + s64, 0.f) * 0.015625f;
    float lo  = sqrtf(d2p) - sqrtf(d2n) + MARGIN_F;
    lo = lo > 0.f ? lo : 0.f;

    #pragma unroll
    for (int m = 32; m; m >>= 1) lo += __shfl_xor(lo, m);
    __shared__ float part[4];
    if (lane == 0) part[threadIdx.x >> 6] = lo;
    __syncthreads();
    if (threadIdx.x == 0) {
        float bs = part[0] + part[1] + part[2] + part[3];
        atomicAdd(red, (unsigned long long)(bs * 16777216.0f));
        __threadfence();
        unsigned int t = atomicAdd((unsigned int*)(red + 1), 1u);
        if (t == gridDim.x - 1) {
            unsigned long long tot = atomicAdd(red, 0ULL);
            out[0] = (float)((double)tot / 16777216.0 / (double)BN);
        }
    }
}

extern "C" void kernel_launch(void* const* d_in, const int* in_sizes, int n_in,
                              void* d_out, int out_size, void* d_ws, size_t ws_size,
                              hipStream_t stream) {
    const float* emb = (const float*)d_in[0];
    const int*   tgt = (const int*)d_in[1];
    float* out = (float*)d_out;

    float* wsf = (float*)d_ws;
    unsigned short* Eb  = (unsigned short*)wsf;
    unsigned short* EbS = (unsigned short*)(wsf + OFF_EBS);
    float* sq64 = wsf + OFF_SQ;
    float* posV = wsf + OFF_POSV;
    float* negV = wsf + OFF_NEGV;
    unsigned long long* red = (unsigned long long*)(wsf + OFF_RED);

    k_prep<<<BN / 4, 256, 0, stream>>>(emb, Eb, EbS, sq64, red);
    k_mine8<<<(BN / 256) * NSPLIT, 256, 0, stream>>>(Eb, EbS, sq64, tgt, posV, negV);
    k_finm<<<BN / 256, 256, 0, stream>>>(sq64, posV, negV, red, out);
}